// Round 1
// baseline (242.236 us; speedup 1.0000x reference)
//
#include <hip/hip_runtime.h>
#include <math.h>

static constexpr int NA = 9;
static constexpr int NH = 128;
static constexpr int NW = 128;
static constexpr int NC = 4;
static constexpr int CH = 6 + NC;      // 10 channels
static constexpr int TCOLS = 13 + NC;  // 17 target columns
static constexpr float SCALE_INV = 1.0f / 16.0f;
static constexpr int MAXT = 128;

// ANCHORS_PX / 16
__constant__ float c_aw[NA] = {1.f, 2.f, 4.f, 8.f, 16.f, 2.f, 4.f, 8.f, 4.f};
__constant__ float c_ah[NA] = {1.f, 2.f, 4.f, 8.f, 16.f, 4.f, 2.f, 4.f, 8.f};

// accumulator slots (doubles in d_ws)
// 0:S0  1:nProp  2:corrNum  3:corrDen  4:maskCnt  5:lx 6:ly 7:lw 8:lh
// 9:lcls 10:lconfMask 11:nGT 12:nCorrect
static constexpr int NACC = 13;

__device__ __forceinline__ float bcef(float x, float z) {
    return fmaxf(x, 0.f) - x * z + log1pf(expf(-fabsf(x)));
}
__device__ __forceinline__ float invtanh(float y) {
    if (y <= -1.f) return -2.f;
    if (y >= 1.f) return 2.f;
    return 0.5f * logf((1.f + y) / (1.f - y));
}
__device__ __forceinline__ float wred(float v) {
#pragma unroll
    for (int o = 32; o; o >>= 1) v += __shfl_down(v, o, 64);
    return v;
}

__global__ void k_init(double* acc) {
    int i = threadIdx.x;
    if (i < NACC) acc[i] = 0.0;
}

__global__ __launch_bounds__(64) void k_scan(const float* __restrict__ pred,
                                             const float* __restrict__ tgt,
                                             const int* __restrict__ tsz,
                                             double* __restrict__ acc, int T) {
    const int b = blockIdx.x;
    const int lane = threadIdx.x;

    __shared__ int sGi[MAXT], sGj[MAXT], sBest[MAXT], sIgn[MAXT], sValid[MAXT], sTl[MAXT];
    __shared__ float sTx[MAXT], sTy[MAXT], sTw[MAXT], sTh[MAXT];
    __shared__ int cellKey[MAXT];
    __shared__ unsigned char cstate[MAXT][NA];
    __shared__ int recCi[MAXT], recA[MAXT], recT[MAXT];
    __shared__ int sCounts[2];

    const int ts = tsz[b];
    float fGT = 0.f, fCor = 0.f;

    // Phase A: per-target independent work (parallel over lanes)
    for (int t = lane; t < T; t += 64) {
        const float* row = tgt + (size_t)(b * T + t) * TCOLS;
        float gx = row[0] * SCALE_INV, gy = row[1] * SCALE_INV;
        float gh = row[3] * SCALE_INV, gw = row[4] * SCALE_INV;
        int valid = (t < ts) && (gw != 0.f) && (gh != 0.f);
        int gi = (int)gx; gi = gi < 0 ? 0 : (gi > NW - 1 ? NW - 1 : gi);
        int gj = (int)gy; gj = gj < 0 ? 0 : (gj > NH - 1 ? NH - 1 : gj);

        float bestIou = -1.f; int best = 0; int ign = 0;
#pragma unroll
        for (int a = 0; a < NA; a++) {
            float aw = c_aw[a], ah = c_ah[a];
            float inter = (fminf(gw, aw) + 1.f) * (fminf(gh, ah) + 1.f);
            float uni = (gw + 1.f) * (gh + 1.f) + (aw + 1.f) * (ah + 1.f) - inter + 1e-16f;
            float iou = inter / uni;
            if (iou > 0.5f) ign |= (1 << a);
            if (iou > bestIou) { bestIou = iou; best = a; }
        }
        sGi[t] = gi; sGj[t] = gj; sBest[t] = best; sIgn[t] = ign; sValid[t] = valid;
        sTx[t] = invtanh(gx - ((float)gi + 0.5f));
        sTy[t] = invtanh(gy - ((float)gj + 0.5f));
        sTw[t] = logf(gw / c_aw[best] + 1e-16f);
        sTh[t] = logf(gh / c_ah[best] + 1e-16f);

        float cc0 = row[13], cc1 = row[14], cc2 = row[15], cc3 = row[16];
        int tl = 0; float cmax = cc0;
        if (cc1 > cmax) { cmax = cc1; tl = 1; }
        if (cc2 > cmax) { cmax = cc2; tl = 2; }
        if (cc3 > cmax) { cmax = cc3; tl = 3; }
        sTl[t] = tl;

        if (valid) {
            fGT += 1.f;
            const float* p = pred + ((((size_t)b * NA + best) * NH + gj) * NW + gi) * CH;
            float p0 = p[0];
            float px = tanhf(p[1]) + 0.5f + (float)gi;
            float py = tanhf(p[2]) + 0.5f + (float)gj;
            float pw = expf(p[5]) * c_aw[best];
            float ph = expf(p[4]) * c_ah[best];
            float b1x1 = gx - gw, b1x2 = gx + gw, b1y1 = gy - gh, b1y2 = gy + gh;
            float b2x1 = px - pw, b2x2 = px + pw, b2y1 = py - ph, b2y2 = py + ph;
            float iw = fmaxf(fminf(b1x2, b2x2) - fmaxf(b1x1, b2x1) + 1.f, 0.f);
            float ih = fmaxf(fminf(b1y2, b2y2) - fmaxf(b1y1, b2y1) + 1.f, 0.f);
            float inter = iw * ih;
            float a1 = (b1x2 - b1x1 + 1.f) * (b1y2 - b1y1 + 1.f);
            float a2 = (b2x2 - b2x1 + 1.f) * (b2y2 - b2y1 + 1.f);
            float iou = inter / (a1 + a2 - inter + 1e-16f);
            float q0 = p[6], q1 = p[7], q2 = p[8], q3 = p[9];
            int pl = 0; float qm = q0;
            if (q1 > qm) { qm = q1; pl = 1; }
            if (q2 > qm) { qm = q2; pl = 2; }
            if (q3 > qm) { qm = q3; pl = 3; }
            if (iou > 0.5f && pl == sTl[t] && p0 > 0.f) fCor += 1.f;
        }
    }
    __syncthreads();

    // Phase B: sequential replay of the scan (lane 0 only; all state in LDS)
    if (lane == 0) {
        int nCells = 0, nRecs = 0;
        for (int t = 0; t < T; t++) {
            if (!sValid[t]) continue;
            int ck = sGj[t] * NW + sGi[t];
            int ci = -1;
            for (int i = 0; i < nCells; i++)
                if (cellKey[i] == ck) { ci = i; break; }
            if (ci < 0) {
                ci = nCells++; cellKey[ci] = ck;
                for (int a = 0; a < NA; a++) cstate[ci][a] = 0;
            }
            int ign = sIgn[t];
            for (int a = 0; a < NA; a++)
                if ((ign >> a) & 1) cstate[ci][a] |= 0x3;  // touched + conf=0
            int bn = sBest[t];
            cstate[ci][bn] = (unsigned char)((cstate[ci][bn] | 0x5) & ~0x2);  // touched+mask, conf=1
            int ri = -1;
            for (int i = 0; i < nRecs; i++)
                if (recCi[i] == ci && recA[i] == bn) { ri = i; break; }
            if (ri < 0) { ri = nRecs++; recCi[ri] = ci; recA[ri] = bn; }
            recT[ri] = t;  // last writer wins
        }
        sCounts[0] = nCells; sCounts[1] = nRecs;
    }
    __syncthreads();
    const int nCells = sCounts[0], nRecs = sCounts[1];

    // Phase C1: per-(cell,anchor) conf_mask corrections vs default state
    float corrNum = 0.f, corrDen = 0.f, lconfM = 0.f, maskCnt = 0.f;
    for (int item = lane; item < nCells * NA; item += 64) {
        int ci = item / NA, a = item - ci * NA;
        int st = cstate[ci][a];
        if (!(st & 1)) continue;
        int ck = cellKey[ci]; int gj = ck >> 7, gi = ck & (NW - 1);
        float conf = pred[((((size_t)b * NA + a) * NH + gj) * NW + gi) * CH];
        float bce0 = bcef(conf, 0.f);
        if (st & 0x4) {  // masked cell (tconf=1)
            float confFinal = (st & 0x2) ? 0.f : 1.f;
            float cmf = confFinal - 1.f;  // 0 or -1
            float bce1 = bcef(conf, 1.f);
            corrNum += bce1 * cmf - bce0;
            corrDen += cmf - 1.f;
            lconfM += bce1;
            maskCnt += 1.f;
        } else if (st & 0x2) {  // ignored, unmasked: cmf = 0
            corrNum -= bce0;
            corrDen -= 1.f;
        }
    }

    // Phase C2: masked-cell coordinate + class losses (last-writer records)
    float lx = 0.f, ly = 0.f, lw = 0.f, lh = 0.f, lcls = 0.f;
    for (int r = lane; r < nRecs; r += 64) {
        int t = recT[r];
        int ci = recCi[r], a = recA[r];
        int ck = cellKey[ci]; int gj = ck >> 7, gi = ck & (NW - 1);
        const float* p = pred + ((((size_t)b * NA + a) * NH + gj) * NW + gi) * CH;
        float dx = p[1] - sTx[t], dy = p[2] - sTy[t];
        float dw = p[5] - sTw[t], dh = p[4] - sTh[t];
        lx += dx * dx; ly += dy * dy; lw += dw * dw; lh += dh * dh;
        float q0 = p[6], q1 = p[7], q2 = p[8], q3 = p[9];
        float m = fmaxf(fmaxf(q0, q1), fmaxf(q2, q3));
        float lse = m + logf(expf(q0 - m) + expf(q1 - m) + expf(q2 - m) + expf(q3 - m));
        lcls += lse - p[6 + sTl[t]];
    }

    float v;
    v = wred(corrNum); if (lane == 0) atomicAdd(&acc[2], (double)v);
    v = wred(corrDen); if (lane == 0) atomicAdd(&acc[3], (double)v);
    v = wred(maskCnt); if (lane == 0) atomicAdd(&acc[4], (double)v);
    v = wred(lx);      if (lane == 0) atomicAdd(&acc[5], (double)v);
    v = wred(ly);      if (lane == 0) atomicAdd(&acc[6], (double)v);
    v = wred(lw);      if (lane == 0) atomicAdd(&acc[7], (double)v);
    v = wred(lh);      if (lane == 0) atomicAdd(&acc[8], (double)v);
    v = wred(lcls);    if (lane == 0) atomicAdd(&acc[9], (double)v);
    v = wred(lconfM);  if (lane == 0) atomicAdd(&acc[10], (double)v);
    v = wred(fGT);     if (lane == 0) atomicAdd(&acc[11], (double)v);
    v = wred(fCor);    if (lane == 0) atomicAdd(&acc[12], (double)v);
}

__global__ __launch_bounds__(256) void k_bg(const float* __restrict__ pred,
                                            double* __restrict__ acc, long long total) {
    __shared__ float sdat[2][4];
    float s0 = 0.f, npos = 0.f;
    long long stride = (long long)gridDim.x * blockDim.x;
    for (long long i = (long long)blockIdx.x * blockDim.x + threadIdx.x; i < total; i += stride) {
        float conf = pred[i * CH];
        s0 += fmaxf(conf, 0.f) + log1pf(expf(-fabsf(conf)));
        npos += (conf > 0.f) ? 1.f : 0.f;
    }
    s0 = wred(s0); npos = wred(npos);
    int wid = threadIdx.x >> 6;
    if ((threadIdx.x & 63) == 0) { sdat[0][wid] = s0; sdat[1][wid] = npos; }
    __syncthreads();
    if (threadIdx.x == 0) {
        float a0 = 0.f, a1 = 0.f;
        for (int w = 0; w < 4; w++) { a0 += sdat[0][w]; a1 += sdat[1][w]; }
        atomicAdd(&acc[0], (double)a0);
        atomicAdd(&acc[1], (double)a1);
    }
}

__global__ void k_fin(const double* __restrict__ acc, float* __restrict__ out,
                      double totalCells, int nB) {
    double S0 = acc[0], nProp = acc[1], corrNum = acc[2], corrDen = acc[3];
    double maskCnt = acc[4];
    double lx = acc[5], ly = acc[6], lw = acc[7], lh = acc[8];
    double lcls = acc[9], lconfM = acc[10], nGT = acc[11], nCor = acc[12];

    double msum = fmax(maskCnt, 1.0);
    double cden = fmax(totalCells + corrDen, 1.0);
    double loss_conf = 1.25 * (S0 + corrNum) / cden + lconfM / msum;
    double lx_ = lx / msum, ly_ = ly / msum, lw_ = lw / msum, lh_ = lh / msum;
    double lcls_ = (lcls / msum) / (double)nB;
    double coord = lx_ + ly_ + lw_ + lh_;
    double loss = coord + loss_conf + lcls_;
    double recall = (nGT > 0.0) ? nCor / fmax(nGT, 1.0) : 1.0;
    double precision = (nProp > 0.0) ? nCor / fmax(nProp, 1.0) : 1.0;

    out[0] = (float)loss;
    out[1] = (float)coord;
    out[2] = (float)loss_conf;
    out[3] = (float)lcls_;
    out[4] = (float)recall;
    out[5] = (float)precision;
}

extern "C" void kernel_launch(void* const* d_in, const int* in_sizes, int n_in,
                              void* d_out, int out_size, void* d_ws, size_t ws_size,
                              hipStream_t stream) {
    const float* pred = (const float*)d_in[0];
    const float* tgt = (const float*)d_in[1];
    const int* tsz = (const int*)d_in[2];
    int nB = in_sizes[2];
    int T = in_sizes[1] / (nB * TCOLS);
    long long total = (long long)nB * NA * NH * NW;

    double* acc = (double*)d_ws;
    float* out = (float*)d_out;

    hipLaunchKernelGGL(k_init, dim3(1), dim3(64), 0, stream, acc);
    hipLaunchKernelGGL(k_scan, dim3(nB), dim3(64), 0, stream, pred, tgt, tsz, acc, T);
    hipLaunchKernelGGL(k_bg, dim3(1024), dim3(256), 0, stream, pred, acc, total);
    hipLaunchKernelGGL(k_fin, dim3(1), dim3(1), 0, stream, acc, out, (double)total, nB);
}

// Round 2
// 119.488 us; speedup vs baseline: 2.0273x; 2.0273x over previous
//
#include <hip/hip_runtime.h>
#include <math.h>

static constexpr int NA = 9;
static constexpr int NH = 128;
static constexpr int NW = 128;
static constexpr int NC = 4;
static constexpr int CH = 6 + NC;      // 10 channels
static constexpr int TCOLS = 13 + NC;  // 17 target columns
static constexpr float SCALE_INV = 1.0f / 16.0f;
static constexpr int MAXT = 128;

// ANCHORS_PX / 16
__constant__ float c_aw[NA] = {1.f, 2.f, 4.f, 8.f, 16.f, 2.f, 4.f, 8.f, 4.f};
__constant__ float c_ah[NA] = {1.f, 2.f, 4.f, 8.f, 16.f, 4.f, 2.f, 4.f, 8.f};

// accumulator slots (doubles in d_ws)
// 0:S0  1:nProp  2:corrNum  3:corrDen  4:maskCnt  5:lx 6:ly 7:lw 8:lh
// 9:lcls 10:lconfMask 11:nGT 12:nCorrect
static constexpr int NACC = 13;

__device__ __forceinline__ float bcef(float x, float z) {
    return fmaxf(x, 0.f) - x * z + log1pf(expf(-fabsf(x)));
}
__device__ __forceinline__ float invtanh(float y) {
    if (y <= -1.f) return -2.f;
    if (y >= 1.f) return 2.f;
    return 0.5f * logf((1.f + y) / (1.f - y));
}
__device__ __forceinline__ float wred(float v) {
#pragma unroll
    for (int o = 32; o; o >>= 1) v += __shfl_down(v, o, 64);
    return v;
}

__global__ void k_init(double* acc) {
    int i = threadIdx.x;
    if (i < NACC) acc[i] = 0.0;
}

// One wave per batch. Phase A: per-target independent work (parallel).
// Phase B/C: parallel last-writer resolution via unique priorities
// pri = 2*t + (touch-is-best ? 1 : 0)  -- exactly the reference's write order
// (within a step, best-set overrides ignore-clear; across steps later wins).
__global__ __launch_bounds__(64) void k_scan(const float* __restrict__ pred,
                                             const float* __restrict__ tgt,
                                             const int* __restrict__ tsz,
                                             double* __restrict__ acc, int T) {
    const int b = blockIdx.x;
    const int lane = threadIdx.x;

    // packed per-target word: bit0 valid | bits1-4 best | bits5-13 ign mask | bits14+ cell
    __shared__ int sPack[MAXT];
    __shared__ float sTx[MAXT], sTy[MAXT], sTw[MAXT], sTh[MAXT];
    __shared__ int sTl[MAXT];

    const int ts = tsz[b];
    float fGT = 0.f, fCor = 0.f;

    // ---- Phase A: per-target independent work ----
    for (int t = lane; t < T; t += 64) {
        const float* row = tgt + (size_t)(b * T + t) * TCOLS;
        float gx = row[0] * SCALE_INV, gy = row[1] * SCALE_INV;
        float gh = row[3] * SCALE_INV, gw = row[4] * SCALE_INV;
        int valid = (t < ts) && (gw != 0.f) && (gh != 0.f);
        int gi = (int)gx; gi = gi < 0 ? 0 : (gi > NW - 1 ? NW - 1 : gi);
        int gj = (int)gy; gj = gj < 0 ? 0 : (gj > NH - 1 ? NH - 1 : gj);

        float bestIou = -1.f; int best = 0; int ign = 0;
#pragma unroll
        for (int a = 0; a < NA; a++) {
            float aw = c_aw[a], ah = c_ah[a];
            float inter = (fminf(gw, aw) + 1.f) * (fminf(gh, ah) + 1.f);
            float uni = (gw + 1.f) * (gh + 1.f) + (aw + 1.f) * (ah + 1.f) - inter + 1e-16f;
            float iou = inter / uni;
            if (iou > 0.5f) ign |= (1 << a);
            if (iou > bestIou) { bestIou = iou; best = a; }
        }
        sPack[t] = (valid ? 1 : 0) | (best << 1) | (ign << 5) | ((gj * NW + gi) << 14);
        sTx[t] = invtanh(gx - ((float)gi + 0.5f));
        sTy[t] = invtanh(gy - ((float)gj + 0.5f));
        sTw[t] = logf(gw / c_aw[best] + 1e-16f);
        sTh[t] = logf(gh / c_ah[best] + 1e-16f);

        float cc0 = row[13], cc1 = row[14], cc2 = row[15], cc3 = row[16];
        int tl = 0; float cmax = cc0;
        if (cc1 > cmax) { cmax = cc1; tl = 1; }
        if (cc2 > cmax) { cmax = cc2; tl = 2; }
        if (cc3 > cmax) { cmax = cc3; tl = 3; }
        sTl[t] = tl;

        if (valid) {
            fGT += 1.f;
            const float* p = pred + ((((size_t)b * NA + best) * NH + gj) * NW + gi) * CH;
            float p0 = p[0];
            float px = tanhf(p[1]) + 0.5f + (float)gi;
            float py = tanhf(p[2]) + 0.5f + (float)gj;
            float pw = expf(p[5]) * c_aw[best];
            float ph = expf(p[4]) * c_ah[best];
            float b1x1 = gx - gw, b1x2 = gx + gw, b1y1 = gy - gh, b1y2 = gy + gh;
            float b2x1 = px - pw, b2x2 = px + pw, b2y1 = py - ph, b2y2 = py + ph;
            float iw = fmaxf(fminf(b1x2, b2x2) - fmaxf(b1x1, b2x1) + 1.f, 0.f);
            float ih = fmaxf(fminf(b1y2, b2y2) - fmaxf(b1y1, b2y1) + 1.f, 0.f);
            float inter = iw * ih;
            float a1 = (b1x2 - b1x1 + 1.f) * (b1y2 - b1y1 + 1.f);
            float a2 = (b2x2 - b2x1 + 1.f) * (b2y2 - b2y1 + 1.f);
            float iou = inter / (a1 + a2 - inter + 1e-16f);
            float q0 = p[6], q1 = p[7], q2 = p[8], q3 = p[9];
            int pl = 0; float qm = q0;
            if (q1 > qm) { qm = q1; pl = 1; }
            if (q2 > qm) { qm = q2; pl = 2; }
            if (q3 > qm) { qm = q3; pl = 3; }
            if (iou > 0.5f && pl == tl && p0 > 0.f) fCor += 1.f;
        }
    }
    __syncthreads();

    // ---- Phase C1: per-(target,anchor) touch items; winner (max priority)
    // per (cell,anchor) contributes the conf_mask correction vs the dense
    // baseline (default cmf=1, tconf=0). ----
    float corrNum = 0.f, corrDen = 0.f, lconfM = 0.f, maskCnt = 0.f;
    const int nItems = T * NA;
    for (int item = lane; item < nItems; item += 64) {
        int t = item / NA, a = item - t * NA;
        int p = sPack[t];
        if (!(p & 1)) continue;
        int myCell = p >> 14;
        int myBest = (p >> 1) & 0xF;
        int myPri;
        if (myBest == a) myPri = 2 * t + 1;
        else if ((p >> (5 + a)) & 1) myPri = 2 * t;
        else continue;

        int maxPri = -1, anyBest = 0;
        for (int u = 0; u < T; u++) {
            int q = sPack[u];
            if (!(q & 1)) continue;
            if ((q >> 14) != myCell) continue;
            int ub = (q >> 1) & 0xF;
            if (ub == a) { maxPri = max(maxPri, 2 * u + 1); anyBest = 1; }
            else if ((q >> (5 + a)) & 1) maxPri = max(maxPri, 2 * u);
        }
        if (maxPri != myPri) continue;  // not the canonical representative

        int gj = myCell >> 7, gi = myCell & (NW - 1);
        float conf = pred[((((size_t)b * NA + a) * NH + gj) * NW + gi) * CH];
        float bce0 = bcef(conf, 0.f);
        if (anyBest) {                      // masked cell: mask=1, tconf=1
            float confFinal = (maxPri & 1) ? 1.f : 0.f;   // best last -> cm=1
            float cmf = confFinal - 1.f;                  // 0 or -1
            float bce1 = bcef(conf, 1.f);
            corrNum += bce1 * cmf - bce0;
            corrDen += cmf - 1.f;
            lconfM += bce1;
            maskCnt += 1.f;
        } else {                            // touched via ignore only: cmf=0
            corrNum -= bce0;
            corrDen -= 1.f;
        }
    }

    // ---- Phase C2: last valid writer per (cell,best) contributes coord+cls ----
    float lx = 0.f, ly = 0.f, lw = 0.f, lh = 0.f, lcls = 0.f;
    for (int t = lane; t < T; t += 64) {
        int p = sPack[t];
        if (!(p & 1)) continue;
        int myCell = p >> 14, myBest = (p >> 1) & 0xF;
        bool last = true;
        for (int u = t + 1; u < T; u++) {
            int q = sPack[u];
            if ((q & 1) && ((q >> 14) == myCell) && (((q >> 1) & 0xF) == myBest)) {
                last = false; break;
            }
        }
        if (!last) continue;
        int gj = myCell >> 7, gi = myCell & (NW - 1);
        const float* pp = pred + ((((size_t)b * NA + myBest) * NH + gj) * NW + gi) * CH;
        float dx = pp[1] - sTx[t], dy = pp[2] - sTy[t];
        float dw = pp[5] - sTw[t], dh = pp[4] - sTh[t];
        lx += dx * dx; ly += dy * dy; lw += dw * dw; lh += dh * dh;
        float q0 = pp[6], q1 = pp[7], q2 = pp[8], q3 = pp[9];
        float m = fmaxf(fmaxf(q0, q1), fmaxf(q2, q3));
        float lse = m + logf(expf(q0 - m) + expf(q1 - m) + expf(q2 - m) + expf(q3 - m));
        lcls += lse - pp[6 + sTl[t]];
    }

    float v;
    v = wred(corrNum); if (lane == 0) atomicAdd(&acc[2], (double)v);
    v = wred(corrDen); if (lane == 0) atomicAdd(&acc[3], (double)v);
    v = wred(maskCnt); if (lane == 0) atomicAdd(&acc[4], (double)v);
    v = wred(lx);      if (lane == 0) atomicAdd(&acc[5], (double)v);
    v = wred(ly);      if (lane == 0) atomicAdd(&acc[6], (double)v);
    v = wred(lw);      if (lane == 0) atomicAdd(&acc[7], (double)v);
    v = wred(lh);      if (lane == 0) atomicAdd(&acc[8], (double)v);
    v = wred(lcls);    if (lane == 0) atomicAdd(&acc[9], (double)v);
    v = wred(lconfM);  if (lane == 0) atomicAdd(&acc[10], (double)v);
    v = wred(fGT);     if (lane == 0) atomicAdd(&acc[11], (double)v);
    v = wred(fCor);    if (lane == 0) atomicAdd(&acc[12], (double)v);
}

// Dense background pass: coalesced float4 over the full prediction array.
// Every 64B line holds a conf value (stride 40B), so full-array HBM traffic
// is mandatory; float4 streaming gets us to copy-kernel bandwidth.
__global__ __launch_bounds__(256) void k_bg(const float4* __restrict__ pred4,
                                            double* __restrict__ acc, int n4) {
    __shared__ float sdat[2][4];
    float s0 = 0.f, npos = 0.f;
    int stride = gridDim.x * blockDim.x;
    for (int i = blockIdx.x * blockDim.x + threadIdx.x; i < n4; i += stride) {
        float4 v = pred4[i];
        int r = (4 * i) % 10;   // element index mod 10; conf sits at r==0 (v.x) or r==8 (v.z)
        if (r == 0 || r == 8) {
            float conf = (r == 0) ? v.x : v.z;
            s0 += fmaxf(conf, 0.f) + log1pf(expf(-fabsf(conf)));
            npos += (conf > 0.f) ? 1.f : 0.f;
        }
    }
    s0 = wred(s0); npos = wred(npos);
    int wid = threadIdx.x >> 6;
    if ((threadIdx.x & 63) == 0) { sdat[0][wid] = s0; sdat[1][wid] = npos; }
    __syncthreads();
    if (threadIdx.x == 0) {
        float a0 = 0.f, a1 = 0.f;
        for (int w = 0; w < 4; w++) { a0 += sdat[0][w]; a1 += sdat[1][w]; }
        atomicAdd(&acc[0], (double)a0);
        atomicAdd(&acc[1], (double)a1);
    }
}

__global__ void k_fin(const double* __restrict__ acc, float* __restrict__ out,
                      double totalCells, int nB) {
    double S0 = acc[0], nProp = acc[1], corrNum = acc[2], corrDen = acc[3];
    double maskCnt = acc[4];
    double lx = acc[5], ly = acc[6], lw = acc[7], lh = acc[8];
    double lcls = acc[9], lconfM = acc[10], nGT = acc[11], nCor = acc[12];

    double msum = fmax(maskCnt, 1.0);
    double cden = fmax(totalCells + corrDen, 1.0);
    double loss_conf = 1.25 * (S0 + corrNum) / cden + lconfM / msum;
    double lx_ = lx / msum, ly_ = ly / msum, lw_ = lw / msum, lh_ = lh / msum;
    double lcls_ = (lcls / msum) / (double)nB;
    double coord = lx_ + ly_ + lw_ + lh_;
    double loss = coord + loss_conf + lcls_;
    double recall = (nGT > 0.0) ? nCor / fmax(nGT, 1.0) : 1.0;
    double precision = (nProp > 0.0) ? nCor / fmax(nProp, 1.0) : 1.0;

    out[0] = (float)loss;
    out[1] = (float)coord;
    out[2] = (float)loss_conf;
    out[3] = (float)lcls_;
    out[4] = (float)recall;
    out[5] = (float)precision;
}

extern "C" void kernel_launch(void* const* d_in, const int* in_sizes, int n_in,
                              void* d_out, int out_size, void* d_ws, size_t ws_size,
                              hipStream_t stream) {
    const float* pred = (const float*)d_in[0];
    const float* tgt = (const float*)d_in[1];
    const int* tsz = (const int*)d_in[2];
    int nB = in_sizes[2];
    int T = in_sizes[1] / (nB * TCOLS);
    long long total = (long long)nB * NA * NH * NW;
    int n4 = (int)(total * CH / 4);

    double* acc = (double*)d_ws;
    float* out = (float*)d_out;

    hipLaunchKernelGGL(k_init, dim3(1), dim3(64), 0, stream, acc);
    hipLaunchKernelGGL(k_scan, dim3(nB), dim3(64), 0, stream, pred, tgt, tsz, acc, T);
    hipLaunchKernelGGL(k_bg, dim3(2048), dim3(256), 0, stream, (const float4*)pred, acc, n4);
    hipLaunchKernelGGL(k_fin, dim3(1), dim3(1), 0, stream, acc, out, (double)total, nB);
}

// Round 3
// 73.267 us; speedup vs baseline: 3.3062x; 1.6309x over previous
//
#include <hip/hip_runtime.h>
#include <math.h>

static constexpr int NA = 9;
static constexpr int NH = 128;
static constexpr int NW = 128;
static constexpr int NC = 4;
static constexpr int CH = 6 + NC;      // 10 channels
static constexpr int TCOLS = 13 + NC;  // 17 target columns
static constexpr float SCALE_INV = 1.0f / 16.0f;
static constexpr int MAXT = 128;
static constexpr int NBG = 1024;       // k_bg grid
static constexpr int SCAN_STRIDE = 16; // floats per scan-block partial record

// ANCHORS_PX / 16
__constant__ float c_aw[NA] = {1.f, 2.f, 4.f, 8.f, 16.f, 2.f, 4.f, 8.f, 4.f};
__constant__ float c_ah[NA] = {1.f, 2.f, 4.f, 8.f, 16.f, 4.f, 2.f, 4.f, 8.f};

// scan partial slots: 0 corrNum, 1 corrDen, 2 maskCnt, 3 lx, 4 ly, 5 lw,
// 6 lh, 7 lcls, 8 lconfM, 9 nGT, 10 nCor
static constexpr int NSLOT = 11;

__device__ __forceinline__ float bcef(float x, float z) {
    return fmaxf(x, 0.f) - x * z + log1pf(expf(-fabsf(x)));
}
__device__ __forceinline__ float invtanh(float y) {
    if (y <= -1.f) return -2.f;
    if (y >= 1.f) return 2.f;
    return 0.5f * logf((1.f + y) / (1.f - y));
}
__device__ __forceinline__ float wred(float v) {
#pragma unroll
    for (int o = 32; o; o >>= 1) v += __shfl_down(v, o, 64);
    return v;
}

// One wave per batch. Phase A: per-target independent work (parallel).
// Phase C: parallel last-writer resolution via unique priorities
// pri = 2*t + (touch-is-best ? 1 : 0) -- exactly the reference's write order.
__global__ __launch_bounds__(64) void k_scan(const float* __restrict__ pred,
                                             const float* __restrict__ tgt,
                                             const int* __restrict__ tsz,
                                             float* __restrict__ scanPart, int T) {
    const int b = blockIdx.x;
    const int lane = threadIdx.x;

    // packed per-target word: bit0 valid | bits1-4 best | bits5-13 ign | bits14+ cell
    __shared__ int sPack[MAXT];
    __shared__ float sTx[MAXT], sTy[MAXT], sTw[MAXT], sTh[MAXT];
    __shared__ int sTl[MAXT];

    const int ts = tsz[b];
    float fGT = 0.f, fCor = 0.f;

    // ---- Phase A ----
    for (int t = lane; t < T; t += 64) {
        const float* row = tgt + (size_t)(b * T + t) * TCOLS;
        float gx = row[0] * SCALE_INV, gy = row[1] * SCALE_INV;
        float gh = row[3] * SCALE_INV, gw = row[4] * SCALE_INV;
        int valid = (t < ts) && (gw != 0.f) && (gh != 0.f);
        int gi = (int)gx; gi = gi < 0 ? 0 : (gi > NW - 1 ? NW - 1 : gi);
        int gj = (int)gy; gj = gj < 0 ? 0 : (gj > NH - 1 ? NH - 1 : gj);

        float bestIou = -1.f; int best = 0; int ign = 0;
#pragma unroll
        for (int a = 0; a < NA; a++) {
            float aw = c_aw[a], ah = c_ah[a];
            float inter = (fminf(gw, aw) + 1.f) * (fminf(gh, ah) + 1.f);
            float uni = (gw + 1.f) * (gh + 1.f) + (aw + 1.f) * (ah + 1.f) - inter + 1e-16f;
            float iou = inter / uni;
            if (iou > 0.5f) ign |= (1 << a);
            if (iou > bestIou) { bestIou = iou; best = a; }
        }
        sPack[t] = (valid ? 1 : 0) | (best << 1) | (ign << 5) | ((gj * NW + gi) << 14);
        sTx[t] = invtanh(gx - ((float)gi + 0.5f));
        sTy[t] = invtanh(gy - ((float)gj + 0.5f));
        sTw[t] = logf(gw / c_aw[best] + 1e-16f);
        sTh[t] = logf(gh / c_ah[best] + 1e-16f);

        float cc0 = row[13], cc1 = row[14], cc2 = row[15], cc3 = row[16];
        int tl = 0; float cmax = cc0;
        if (cc1 > cmax) { cmax = cc1; tl = 1; }
        if (cc2 > cmax) { cmax = cc2; tl = 2; }
        if (cc3 > cmax) { cmax = cc3; tl = 3; }
        sTl[t] = tl;

        if (valid) {
            fGT += 1.f;
            const float* p = pred + ((((size_t)b * NA + best) * NH + gj) * NW + gi) * CH;
            float p0 = p[0];
            float px = tanhf(p[1]) + 0.5f + (float)gi;
            float py = tanhf(p[2]) + 0.5f + (float)gj;
            float pw = expf(p[5]) * c_aw[best];
            float ph = expf(p[4]) * c_ah[best];
            float b1x1 = gx - gw, b1x2 = gx + gw, b1y1 = gy - gh, b1y2 = gy + gh;
            float b2x1 = px - pw, b2x2 = px + pw, b2y1 = py - ph, b2y2 = py + ph;
            float iw = fmaxf(fminf(b1x2, b2x2) - fmaxf(b1x1, b2x1) + 1.f, 0.f);
            float ih = fmaxf(fminf(b1y2, b2y2) - fmaxf(b1y1, b2y1) + 1.f, 0.f);
            float inter = iw * ih;
            float a1 = (b1x2 - b1x1 + 1.f) * (b1y2 - b1y1 + 1.f);
            float a2 = (b2x2 - b2x1 + 1.f) * (b2y2 - b2y1 + 1.f);
            float iou = inter / (a1 + a2 - inter + 1e-16f);
            float q0 = p[6], q1 = p[7], q2 = p[8], q3 = p[9];
            int pl = 0; float qm = q0;
            if (q1 > qm) { qm = q1; pl = 1; }
            if (q2 > qm) { qm = q2; pl = 2; }
            if (q3 > qm) { qm = q3; pl = 3; }
            if (iou > 0.5f && pl == tl && p0 > 0.f) fCor += 1.f;
        }
    }
    __syncthreads();

    // ---- Phase C1: conf_mask corrections vs dense baseline ----
    float corrNum = 0.f, corrDen = 0.f, lconfM = 0.f, maskCnt = 0.f;
    const int nItems = T * NA;
    for (int item = lane; item < nItems; item += 64) {
        int t = item / NA, a = item - t * NA;
        int p = sPack[t];
        if (!(p & 1)) continue;
        int myCell = p >> 14;
        int myBest = (p >> 1) & 0xF;
        int myPri;
        if (myBest == a) myPri = 2 * t + 1;
        else if ((p >> (5 + a)) & 1) myPri = 2 * t;
        else continue;

        int maxPri = -1, anyBest = 0;
        for (int u = 0; u < T; u++) {
            int q = sPack[u];
            if (!(q & 1)) continue;
            if ((q >> 14) != myCell) continue;
            int ub = (q >> 1) & 0xF;
            if (ub == a) { maxPri = max(maxPri, 2 * u + 1); anyBest = 1; }
            else if ((q >> (5 + a)) & 1) maxPri = max(maxPri, 2 * u);
        }
        if (maxPri != myPri) continue;  // not the canonical representative

        int gj = myCell >> 7, gi = myCell & (NW - 1);
        float conf = pred[((((size_t)b * NA + a) * NH + gj) * NW + gi) * CH];
        float bce0 = bcef(conf, 0.f);
        if (anyBest) {                      // masked cell: mask=1, tconf=1
            float confFinal = (maxPri & 1) ? 1.f : 0.f;
            float cmf = confFinal - 1.f;    // 0 or -1
            float bce1 = bcef(conf, 1.f);
            corrNum += bce1 * cmf - bce0;
            corrDen += cmf - 1.f;
            lconfM += bce1;
            maskCnt += 1.f;
        } else {                            // ignore-only: cmf = 0
            corrNum -= bce0;
            corrDen -= 1.f;
        }
    }

    // ---- Phase C2: last valid writer per (cell,best): coord + cls ----
    float lx = 0.f, ly = 0.f, lw = 0.f, lh = 0.f, lcls = 0.f;
    for (int t = lane; t < T; t += 64) {
        int p = sPack[t];
        if (!(p & 1)) continue;
        int myCell = p >> 14, myBest = (p >> 1) & 0xF;
        bool last = true;
        for (int u = t + 1; u < T; u++) {
            int q = sPack[u];
            if ((q & 1) && ((q >> 14) == myCell) && (((q >> 1) & 0xF) == myBest)) {
                last = false; break;
            }
        }
        if (!last) continue;
        int gj = myCell >> 7, gi = myCell & (NW - 1);
        const float* pp = pred + ((((size_t)b * NA + myBest) * NH + gj) * NW + gi) * CH;
        float dx = pp[1] - sTx[t], dy = pp[2] - sTy[t];
        float dw = pp[5] - sTw[t], dh = pp[4] - sTh[t];
        lx += dx * dx; ly += dy * dy; lw += dw * dw; lh += dh * dh;
        float q0 = pp[6], q1 = pp[7], q2 = pp[8], q3 = pp[9];
        float m = fmaxf(fmaxf(q0, q1), fmaxf(q2, q3));
        float lse = m + logf(expf(q0 - m) + expf(q1 - m) + expf(q2 - m) + expf(q3 - m));
        lcls += lse - pp[6 + sTl[t]];
    }

    float* dst = scanPart + b * SCAN_STRIDE;
    float v;
    v = wred(corrNum); if (lane == 0) dst[0] = v;
    v = wred(corrDen); if (lane == 0) dst[1] = v;
    v = wred(maskCnt); if (lane == 0) dst[2] = v;
    v = wred(lx);      if (lane == 0) dst[3] = v;
    v = wred(ly);      if (lane == 0) dst[4] = v;
    v = wred(lw);      if (lane == 0) dst[5] = v;
    v = wred(lh);      if (lane == 0) dst[6] = v;
    v = wred(lcls);    if (lane == 0) dst[7] = v;
    v = wred(lconfM);  if (lane == 0) dst[8] = v;
    v = wred(fGT);     if (lane == 0) dst[9] = v;
    v = wred(fCor);    if (lane == 0) dst[10] = v;
}

// Dense background pass: scalar loads of ONLY the conf channel (stride 10
// floats). Every 64B line contains a conf, so HBM line traffic is identical
// to streaming the whole array, but issue/lane efficiency is maximal.
// No global atomics: one float2 partial per block.
__global__ __launch_bounds__(256) void k_bg(const float* __restrict__ pred,
                                            float2* __restrict__ bgPart, int nCells) {
    __shared__ float sdat[2][4];
    float s0 = 0.f, npos = 0.f;
    const int stride = gridDim.x * blockDim.x;
    int c = blockIdx.x * blockDim.x + threadIdx.x;
    // 3-way unrolled grid-stride: 3 independent loads in flight per thread
    for (; c + 2 * stride < nCells; c += 3 * stride) {
        float c0 = pred[(size_t)c * CH];
        float c1 = pred[(size_t)(c + stride) * CH];
        float c2 = pred[(size_t)(c + 2 * stride) * CH];
        s0 += fmaxf(c0, 0.f) + log1pf(expf(-fabsf(c0)));
        s0 += fmaxf(c1, 0.f) + log1pf(expf(-fabsf(c1)));
        s0 += fmaxf(c2, 0.f) + log1pf(expf(-fabsf(c2)));
        npos += (c0 > 0.f) ? 1.f : 0.f;
        npos += (c1 > 0.f) ? 1.f : 0.f;
        npos += (c2 > 0.f) ? 1.f : 0.f;
    }
    for (; c < nCells; c += stride) {
        float cv = pred[(size_t)c * CH];
        s0 += fmaxf(cv, 0.f) + log1pf(expf(-fabsf(cv)));
        npos += (cv > 0.f) ? 1.f : 0.f;
    }
    s0 = wred(s0); npos = wred(npos);
    int wid = threadIdx.x >> 6;
    if ((threadIdx.x & 63) == 0) { sdat[0][wid] = s0; sdat[1][wid] = npos; }
    __syncthreads();
    if (threadIdx.x == 0) {
        float a0 = 0.f, a1 = 0.f;
        for (int w = 0; w < 4; w++) { a0 += sdat[0][w]; a1 += sdat[1][w]; }
        bgPart[blockIdx.x] = make_float2(a0, a1);
    }
}

__global__ __launch_bounds__(256) void k_fin(const float* __restrict__ scanPart,
                                             const float2* __restrict__ bgPart,
                                             float* __restrict__ out,
                                             double totalCells, int nB, int nbg) {
    __shared__ double sred[2][4];
    __shared__ double sscan[NSLOT];
    const int tid = threadIdx.x;

    double s0 = 0.0, np = 0.0;
    for (int i = tid; i < nbg; i += 256) {
        float2 v = bgPart[i];
        s0 += (double)v.x; np += (double)v.y;
    }
#pragma unroll
    for (int o = 32; o; o >>= 1) {
        s0 += __shfl_down(s0, o, 64);
        np += __shfl_down(np, o, 64);
    }
    int wid = tid >> 6;
    if ((tid & 63) == 0) { sred[0][wid] = s0; sred[1][wid] = np; }
    if (tid < NSLOT) {
        double s = 0.0;
        for (int b = 0; b < nB; b++) s += (double)scanPart[b * SCAN_STRIDE + tid];
        sscan[tid] = s;
    }
    __syncthreads();
    if (tid == 0) {
        double S0 = sred[0][0] + sred[0][1] + sred[0][2] + sred[0][3];
        double nProp = sred[1][0] + sred[1][1] + sred[1][2] + sred[1][3];
        double corrNum = sscan[0], corrDen = sscan[1], maskCnt = sscan[2];
        double lx = sscan[3], ly = sscan[4], lw = sscan[5], lh = sscan[6];
        double lcls = sscan[7], lconfM = sscan[8], nGT = sscan[9], nCor = sscan[10];

        double msum = fmax(maskCnt, 1.0);
        double cden = fmax(totalCells + corrDen, 1.0);
        double loss_conf = 1.25 * (S0 + corrNum) / cden + lconfM / msum;
        double lx_ = lx / msum, ly_ = ly / msum, lw_ = lw / msum, lh_ = lh / msum;
        double lcls_ = (lcls / msum) / (double)nB;
        double coord = lx_ + ly_ + lw_ + lh_;
        double loss = coord + loss_conf + lcls_;
        double recall = (nGT > 0.0) ? nCor / fmax(nGT, 1.0) : 1.0;
        double precision = (nProp > 0.0) ? nCor / fmax(nProp, 1.0) : 1.0;

        out[0] = (float)loss;
        out[1] = (float)coord;
        out[2] = (float)loss_conf;
        out[3] = (float)lcls_;
        out[4] = (float)recall;
        out[5] = (float)precision;
    }
}

extern "C" void kernel_launch(void* const* d_in, const int* in_sizes, int n_in,
                              void* d_out, int out_size, void* d_ws, size_t ws_size,
                              hipStream_t stream) {
    const float* pred = (const float*)d_in[0];
    const float* tgt = (const float*)d_in[1];
    const int* tsz = (const int*)d_in[2];
    int nB = in_sizes[2];
    int T = in_sizes[1] / (nB * TCOLS);
    long long total = (long long)nB * NA * NH * NW;
    int nCells = (int)total;

    // d_ws layout: [scanPart: nB*SCAN_STRIDE floats][bgPart: NBG float2]
    float* scanPart = (float*)d_ws;
    float2* bgPart = (float2*)((char*)d_ws + (size_t)nB * SCAN_STRIDE * sizeof(float));
    float* out = (float*)d_out;

    hipLaunchKernelGGL(k_bg, dim3(NBG), dim3(256), 0, stream, pred, bgPart, nCells);
    hipLaunchKernelGGL(k_scan, dim3(nB), dim3(64), 0, stream, pred, tgt, tsz, scanPart, T);
    hipLaunchKernelGGL(k_fin, dim3(1), dim3(256), 0, stream, scanPart, bgPart, out,
                       (double)total, nB, NBG);
}